// Round 17
// baseline (582.475 us; speedup 1.0000x reference)
//
#include <hip/hip_runtime.h>
#include <math.h>

// Problem constants: B=32, T=64, I=E=Ha=Hb=256, O=1, P=T-1=63
#define B_   32
#define T_   64
#define P_   63
#define E_   256

typedef _Float16 half8 __attribute__((ext_vector_type(8)));
typedef _Float16 half4 __attribute__((ext_vector_type(4)));
typedef float    f32x4 __attribute__((ext_vector_type(4)));

__device__ __forceinline__ float sigmoidf_(float x) { return 1.0f / (1.0f + __expf(-x)); }
__device__ __forceinline__ float tanhfast_(float x) { float e = __expf(2.0f*x); return 1.0f - 2.0f/(e + 1.0f); }

// Barrier WITHOUT vmcnt drain: only LDS ops must be visible across it.
__device__ __forceinline__ void barrier_lds_() {
    asm volatile("" ::: "memory");
    asm volatile("s_waitcnt lgkmcnt(0)" ::: "memory");
    __builtin_amdgcn_s_barrier();
    asm volatile("" ::: "memory");
}

// ---------------------------------------------------------------- K_prep: all weight->fp16 MFMA A-fragments, one launch.
__global__ __launch_bounds__(64) void k_prep(
    const float* __restrict__ awhh, const float* __restrict__ bwhh,
    const float* __restrict__ awih, const float* __restrict__ bwih,
    const float* __restrict__ beta_w, const float* __restrict__ emb_w, const float* __restrict__ out_w,
    _Float16* __restrict__ wfa, _Float16* __restrict__ wfb,
    _Float16* __restrict__ wifa, _Float16* __restrict__ wifb,
    _Float16* __restrict__ bwf, _Float16* __restrict__ mf)
{
    int bid = blockIdx.x, l = threadIdx.x;
    if (bid < 1664) {
        const float* W; _Float16* dst; float scale = 1.0f; int r;
        if (bid < 384)       { W = awhh;   dst = wfa;  r = bid; }
        else if (bid < 768)  { W = bwhh;   dst = wfb;  r = bid - 384; }
        else if (bid < 1152) { W = awih;   dst = wifa; r = bid - 768; }
        else if (bid < 1536) { W = bwih;   dst = wifb; r = bid - 1152; }
        else                 { W = beta_w; dst = bwf;  r = bid - 1536; scale = 0.5f; }
        int ot = r >> 3, kc = r & 7;
        int orow = ot * 16 + (l & 15);
        int c0   = kc * 32 + (l >> 4) * 8;
        half8 v;
        #pragma unroll
        for (int j = 0; j < 8; ++j) v[j] = (_Float16)(scale * W[(size_t)orow * 256 + c0 + j]);
        *reinterpret_cast<half8*>(&dst[((size_t)r * 64 + l) * 8]) = v;
    } else {
        int r = bid - 1664;     // M^T frags: A[row=i][k=e] = out_w[e]*emb_w[e][i]
        int ot = r >> 3, kc = r & 7;
        int i  = ot * 16 + (l & 15);
        int e0 = kc * 32 + (l >> 4) * 8;
        half8 v;
        #pragma unroll
        for (int j = 0; j < 8; ++j) v[j] = (_Float16)(out_w[e0 + j] * emb_w[(size_t)(e0 + j) * 256 + i]);
        *reinterpret_cast<half8*>(&mf[((size_t)r * 64 + l) * 8]) = v;
    }
}

// ---------------------------------------------------------------- K1: emb (8 rows/block) -> embh, ewh, xh (all fp16)
__global__ __launch_bounds__(256) void k_emb(const float* __restrict__ x,
                                             const float* __restrict__ emb_w,
                                             const float* __restrict__ emb_b,
                                             const float* __restrict__ out_w,
                                             _Float16* __restrict__ embh,
                                             _Float16* __restrict__ ewh,
                                             _Float16* __restrict__ xh) {
    int r0 = blockIdx.x * 8;       // row = t*32 + b
    int tid = threadIdx.x;
    __shared__ float xs[8][E_];
    for (int rr = 0; rr < 8; ++rr) {
        int row = r0 + rr, t = row >> 5, b = row & 31;
        float xv = x[((size_t)b * T_ + t) * E_ + tid];
        xs[rr][tid] = xv;
        xh[((size_t)b * T_ + t) * E_ + tid] = (_Float16)xv;
    }
    __syncthreads();
    float acc[8];
    #pragma unroll
    for (int rr = 0; rr < 8; ++rr) acc[rr] = 0.f;
    const float* wr = emb_w + (size_t)tid * E_;
    for (int c = 0; c < 256; c += 4) {
        float4 wv = *reinterpret_cast<const float4*>(wr + c);
        #pragma unroll
        for (int rr = 0; rr < 8; ++rr) {
            float4 ev = *reinterpret_cast<const float4*>(&xs[rr][c]);
            acc[rr] += wv.x * ev.x + wv.y * ev.y + wv.z * ev.z + wv.w * ev.w;
        }
    }
    float eb = emb_b[tid], ow = out_w[tid];
    #pragma unroll
    for (int rr = 0; rr < 8; ++rr) {
        float v = acc[rr] + eb;
        embh[(size_t)(r0 + rr) * E_ + tid] = (_Float16)v;
        ewh[(size_t)(r0 + rr) * E_ + tid]  = (_Float16)(v * ow);
    }
}

// ---------------------------------------------------------------- K2: gi = wih @ emb^T + bias via MFMA -> packed gp layout
// for the 126-block k_gru_f: gp[(((t*8+w)*3+g3)*2+rt)*512 + l*8 + (i*4+j)],
// dim = 32w+16i+lg*4+j, batch = rt*16+lr. (one coalesced half8 per (gate,rt) per lane.)
__global__ __launch_bounds__(512, 2) void k_gates2(
    const _Float16* __restrict__ embh,
    const _Float16* __restrict__ wifa, const _Float16* __restrict__ wifb,
    const float* __restrict__ abih, const float* __restrict__ abhh,
    const float* __restrict__ bbih, const float* __restrict__ bbhh,
    _Float16* __restrict__ gpa, _Float16* __restrict__ gpb)
{
    __shared__ _Float16 esw[32 * E_];   // 16 KB swizzled emb rows (batch) for this t
    int bid = blockIdx.x;
    int g = bid >> 6, t = bid & 63;
    const _Float16* wif = g ? wifb : wifa;
    const float* bih = g ? bbih : abih;
    const float* bhh = g ? bbhh : abhh;
    _Float16* gp = g ? gpb : gpa;
    int tid = threadIdx.x, w = tid >> 6, l = tid & 63, lg = l >> 4, lr = l & 15;

    #pragma unroll
    for (int q = 0; q < 2; ++q) {
        int idx = q * 512 + tid;
        int b = idx >> 5, e0 = (idx & 31) * 8;
        half8 v = *reinterpret_cast<const half8*>(&embh[((size_t)t * 32 + b) * E_ + e0]);
        *reinterpret_cast<half8*>(&esw[b * E_ + (e0 ^ ((b & 7) << 3))]) = v;
    }
    half8 aw[3][2][8];
    #pragma unroll
    for (int g3 = 0; g3 < 3; ++g3)
        #pragma unroll
        for (int i = 0; i < 2; ++i)
            #pragma unroll
            for (int kc = 0; kc < 8; ++kc)
                aw[g3][i][kc] = *reinterpret_cast<const half8*>(
                    &wif[(((size_t)(g3 * 16 + 2 * w + i) * 8 + kc) * 64 + l) * 8]);
    f32x4 acc[3][2][2];
    #pragma unroll
    for (int g3 = 0; g3 < 3; ++g3)
        #pragma unroll
        for (int i = 0; i < 2; ++i)
            #pragma unroll
            for (int rt = 0; rt < 2; ++rt)
                #pragma unroll
                for (int j = 0; j < 4; ++j) {
                    int d = g3 * 256 + 32 * w + 16 * i + lg * 4 + j;
                    acc[g3][i][rt][j] = bih[d] + ((g3 < 2) ? bhh[d] : 0.f);
                }
    __syncthreads();
    #pragma unroll
    for (int kc = 0; kc < 8; ++kc) {
        half8 eb[2];
        #pragma unroll
        for (int rt = 0; rt < 2; ++rt)
            eb[rt] = *reinterpret_cast<const half8*>(
                &esw[(rt * 16 + lr) * E_ + ((kc * 32 + lg * 8) ^ ((lr & 7) << 3))]);
        #pragma unroll
        for (int g3 = 0; g3 < 3; ++g3)
            #pragma unroll
            for (int i = 0; i < 2; ++i)
                #pragma unroll
                for (int rt = 0; rt < 2; ++rt)
                    acc[g3][i][rt] = __builtin_amdgcn_mfma_f32_16x16x32_f16(
                        aw[g3][i][kc], eb[rt], acc[g3][i][rt], 0, 0, 0);
    }
    #pragma unroll
    for (int g3 = 0; g3 < 3; ++g3)
        #pragma unroll
        for (int rt = 0; rt < 2; ++rt) {
            half8 v;
            #pragma unroll
            for (int i = 0; i < 2; ++i)
                #pragma unroll
                for (int j = 0; j < 4; ++j) v[i * 4 + j] = (_Float16)acc[g3][i][rt][j];
            *reinterpret_cast<half8*>(
                &gp[((((size_t)t * 8 + w) * 3 + g3) * 2 + rt) * 512 + l * 8]) = v;
        }
}

// ---------------------------------------------------------------- K3: triangular GRU chains, 126-block (halved W readers).
// block = (g, p): 126 blocks x 512 threads (8 waves). Wave w owns 2 ot-tiles per gate as
// R12, but processes ALL 32 batch rows (rt=2 B-frags per streamed A-frag). Per-CU W stream
// per step unchanged, but block count halves -> per-XCD L2 W traffic halves (the R12-R16
// invariant bottleneck: occupancy/residency knobs were all null, W bytes were constant).
__global__ __launch_bounds__(512, 2) void k_gru_f(
    const _Float16* __restrict__ gpa, const _Float16* __restrict__ gpb,
    const _Float16* __restrict__ wfa, const _Float16* __restrict__ wfb,
    const float* __restrict__ abhh, const float* __restrict__ bbhh,
    const float* __restrict__ alpha_w, const float* __restrict__ alpha_b,
    float* __restrict__ pre, _Float16* __restrict__ hstore)
{
    extern __shared__ char smem[];
    half8*    wlds = reinterpret_cast<half8*>(smem);              // 96 KB: kc 6..7, 48 ot
    _Float16* hsp  = reinterpret_cast<_Float16*>(smem + 98304);   // [2][32][256] = 32 KB
    float*    red  = reinterpret_cast<float*>(smem + 98304 + 32768);  // [2][32][8] = 2 KB

    int bid = blockIdx.x;
    int g   = bid / 63;
    int p   = 62 - (bid % 63);
    int tid = threadIdx.x;
    int w = tid >> 6, l = tid & 63, lg = l >> 4, lr = l & 15;
    const _Float16* gp  = g ? gpb : gpa;
    const _Float16* wf  = g ? wfb : wfa;
    const float*    bhh = g ? bbhh : abhh;

    half8 wreg[3][2][6];
    #pragma unroll
    for (int g3 = 0; g3 < 3; ++g3)
        #pragma unroll
        for (int i = 0; i < 2; ++i) {
            int ot = g3 * 16 + 2 * w + i;
            #pragma unroll
            for (int kc = 0; kc < 6; ++kc)
                wreg[g3][i][kc] = *reinterpret_cast<const half8*>(&wf[((size_t)(ot * 8 + kc) * 64 + l) * 8]);
        }
    #pragma unroll
    for (int q = 0; q < 12; ++q) {
        int idx = q * 512 + tid;
        int ot = idx >> 7, kcs = (idx >> 6) & 1, l2 = idx & 63;
        wlds[idx] = *reinterpret_cast<const half8*>(&wf[((size_t)(ot * 8 + 6 + kcs) * 64 + l2) * 8]);
    }
    float bhn[2][4], awv[2][4];
    #pragma unroll
    for (int i = 0; i < 2; ++i)
        #pragma unroll
        for (int j = 0; j < 4; ++j) {
            int d = 32 * w + 16 * i + lg * 4 + j;
            bhn[i][j] = bhh[512 + d];
            awv[i][j] = alpha_w[d];
        }
    float ab = alpha_b[0];
    float hreg[2][2][4];   // [i][rt][j]
    #pragma unroll
    for (int i = 0; i < 2; ++i)
        #pragma unroll
        for (int rt = 0; rt < 2; ++rt)
            #pragma unroll
            for (int j = 0; j < 4; ++j) hreg[i][rt][j] = 0.f;
    __syncthreads();

    size_t tri = (size_t)p * (p + 1) / 2;

    for (int k = 0; k <= p; ++k) {
        int t_in = p - k;
        int wr = k & 1, rb = wr ^ 1;
        // ---- drain step k-1's pre (g=0): all 32 batch
        if (k > 0 && g == 0 && tid < 32) {
            float s = 0.f;
            #pragma unroll
            for (int q = 0; q < 8; ++q) s += red[(rb * 32 + tid) * 8 + q];
            pre[((size_t)p * T_ + (t_in + 1)) * B_ + tid] = 0.5f * s + ab;
        }
        // ---- gi loads: one half8 per (gate, rt)
        half8 gch[3][2];
        {
            const _Float16* gq = gp + (((size_t)(t_in * 8 + w) * 3) * 2) * 512 + l * 8;
            #pragma unroll
            for (int c = 0; c < 3; ++c)
                #pragma unroll
                for (int rt = 0; rt < 2; ++rt)
                    gch[c][rt] = *reinterpret_cast<const half8*>(gq + (size_t)(c * 2 + rt) * 512);
        }
        // ---- MFMA: acc = W @ h (skip at k=0)
        f32x4 acc[3][2][2];
        #pragma unroll
        for (int g3 = 0; g3 < 3; ++g3)
            #pragma unroll
            for (int i = 0; i < 2; ++i)
                #pragma unroll
                for (int rt = 0; rt < 2; ++rt)
                    #pragma unroll
                    for (int j = 0; j < 4; ++j) acc[g3][i][rt][j] = 0.f;
        if (k > 0) {
            half8 bhv[2][2];   // [kc parity][rt]
            #pragma unroll
            for (int rt = 0; rt < 2; ++rt) {
                int cb = (lg * 8) ^ ((lr & 7) << 3);
                bhv[0][rt] = *reinterpret_cast<const half8*>(&hsp[(rb * 32 + rt * 16 + lr) * 256 + cb]);
            }
            #pragma unroll
            for (int kc = 0; kc < 8; ++kc) {
                if (kc < 7) {
                    #pragma unroll
                    for (int rt = 0; rt < 2; ++rt) {
                        int cb = ((kc + 1) * 32 + lg * 8) ^ ((lr & 7) << 3);
                        bhv[(kc + 1) & 1][rt] = *reinterpret_cast<const half8*>(&hsp[(rb * 32 + rt * 16 + lr) * 256 + cb]);
                    }
                }
                if (kc < 6) {
                    #pragma unroll
                    for (int g3 = 0; g3 < 3; ++g3)
                        #pragma unroll
                        for (int i = 0; i < 2; ++i)
                            #pragma unroll
                            for (int rt = 0; rt < 2; ++rt)
                                acc[g3][i][rt] = __builtin_amdgcn_mfma_f32_16x16x32_f16(
                                    wreg[g3][i][kc], bhv[kc & 1][rt], acc[g3][i][rt], 0, 0, 0);
                } else {
                    #pragma unroll
                    for (int g3 = 0; g3 < 3; ++g3)
                        #pragma unroll
                        for (int i = 0; i < 2; ++i) {
                            half8 wlv = wlds[((g3 * 16 + 2 * w + i) * 2 + (kc - 6)) * 64 + l];
                            #pragma unroll
                            for (int rt = 0; rt < 2; ++rt)
                                acc[g3][i][rt] = __builtin_amdgcn_mfma_f32_16x16x32_f16(
                                    wlv, bhv[kc & 1][rt], acc[g3][i][rt], 0, 0, 0);
                        }
                }
            }
        }
        // ---- nonlinearity + state update + fp16 LDS write (+ hstore for g=1)
        #pragma unroll
        for (int rt = 0; rt < 2; ++rt) {
            _Float16* hdst = hstore + ((tri + (size_t)k) * B_ + rt * 16 + lr) * (size_t)E_ + 32 * w + lg * 4;
            #pragma unroll
            for (int i = 0; i < 2; ++i) {
                half4 hh;
                #pragma unroll
                for (int j = 0; j < 4; ++j) {
                    int e = i * 4 + j;
                    float rg = sigmoidf_(acc[0][i][rt][j] + (float)gch[0][rt][e]);
                    float zg = sigmoidf_(acc[1][i][rt][j] + (float)gch[1][rt][e]);
                    float ng = tanhfast_((float)gch[2][rt][e] + rg * (acc[2][i][rt][j] + bhn[i][j]));
                    float h  = (1.f - zg) * ng + zg * hreg[i][rt][j];
                    hreg[i][rt][j] = h;
                    hh[j] = (_Float16)h;
                }
                int ce = (32 * w + 16 * i + lg * 4) ^ ((lr & 7) << 3);
                *reinterpret_cast<half4*>(&hsp[(wr * 32 + rt * 16 + lr) * 256 + ce]) = hh;
                if (g) *reinterpret_cast<half4*>(hdst + 16 * i) = hh;
            }
        }
        if (!g) {
            #pragma unroll
            for (int rt = 0; rt < 2; ++rt) {
                float pa = 0.f;
                #pragma unroll
                for (int i = 0; i < 2; ++i)
                    #pragma unroll
                    for (int j = 0; j < 4; ++j) pa += hreg[i][rt][j] * awv[i][j];
                pa += __shfl_xor(pa, 16, 64);
                pa += __shfl_xor(pa, 32, 64);
                if (l < 16) red[(wr * 32 + rt * 16 + l) * 8 + w] = pa;
            }
        }
        barrier_lds_();
    }
    // ---- epilogue: drain step p's pre
    if (g == 0 && tid < 32) {
        int wl = p & 1;
        float s = 0.f;
        #pragma unroll
        for (int q = 0; q < 8; ++q) s += red[(wl * 32 + tid) * 8 + q];
        pre[((size_t)p * T_ + 0) * B_ + tid] = 0.5f * s + ab;
    }
}

// ---------------------------------------------------------------- K5: attention tail v3 (R12-exact known-good).
__global__ __launch_bounds__(512, 2) void k_att3(
    const _Float16* __restrict__ hH,
    const _Float16* __restrict__ bwf, const _Float16* __restrict__ mf,
    const float* __restrict__ beta_b,
    const float* __restrict__ pre,
    const _Float16* __restrict__ ewh, const _Float16* __restrict__ xh,
    const float* __restrict__ out_b,
    float* __restrict__ out)
{
    extern __shared__ char smem[];
    _Float16* hs   = reinterpret_cast<_Float16*>(smem);            // [64][256] swz: H then U
    _Float16* es2  = reinterpret_cast<_Float16*>(smem + 32768);    // [64][256] swz: ewh
    _Float16* xs2  = reinterpret_cast<_Float16*>(smem + 65536);    // [64][256] swz: x
    float*    alds = reinterpret_cast<float*>(smem + 98304);       // [64]
    float*    red2 = reinterpret_cast<float*>(smem + 98304 + 256); // [8]
    int tid = threadIdx.x, w = tid >> 6, l = tid & 63, lg = l >> 4, lr = l & 15;

    half8 aw2[2][8], am2[2][8];
    #pragma unroll
    for (int i = 0; i < 2; ++i)
        #pragma unroll
        for (int kc = 0; kc < 8; ++kc) {
            size_t fo = (((size_t)(2 * w + i) * 8 + kc) * 64 + l) * 8;
            aw2[i][kc] = *reinterpret_cast<const half8*>(&bwf[fo]);
            am2[i][kc] = *reinterpret_cast<const half8*>(&mf[fo]);
        }
    float bb2[2][4];
    #pragma unroll
    for (int i = 0; i < 2; ++i)
        #pragma unroll
        for (int j = 0; j < 4; ++j)
            bb2[i][j] = beta_b[(2 * w + i) * 16 + lg * 4 + j];
    float ob = out_b[0];

    for (int it = 0; it < 8; ++it) {
        int pair = blockIdx.x * 8 + it;
        int p = pair >> 5, b = pair & 31;
        size_t tri = (size_t)p * (p + 1) / 2;
        // ---- stage H (reversed), ewh, x (coalesced 16B, swizzled)
        #pragma unroll
        for (int q = 0; q < 4; ++q) {
            int idx = q * 512 + tid;
            int k = idx >> 5, e0 = (idx & 31) * 8;
            int sw = e0 ^ ((k & 7) << 3);
            half8 hv, ev;
            if (k <= p) {
                hv = *reinterpret_cast<const half8*>(&hH[((tri + (size_t)(p - k)) * B_ + b) * 256 + e0]);
                ev = *reinterpret_cast<const half8*>(&ewh[((size_t)k * B_ + b) * 256 + e0]);
            } else {
                #pragma unroll
                for (int j = 0; j < 8; ++j) { hv[j] = (_Float16)0.f; ev[j] = (_Float16)0.f; }
            }
            *reinterpret_cast<half8*>(&hs[k * 256 + sw])  = hv;
            *reinterpret_cast<half8*>(&es2[k * 256 + sw]) = ev;
            *reinterpret_cast<half8*>(&xs2[k * 256 + sw]) =
                *reinterpret_cast<const half8*>(&xh[((size_t)b * T_ + k) * 256 + e0]);
        }
        // ---- softmax on wave 0
        if (tid < 64) {
            float v = (tid <= p) ? pre[((size_t)p * T_ + tid) * B_ + b] : -3.4e38f;
            float m = v;
            #pragma unroll
            for (int off = 32; off > 0; off >>= 1) m = fmaxf(m, __shfl_xor(m, off, 64));
            float e = (tid <= p) ? __expf(v - m) : 0.f;
            float s = e;
            #pragma unroll
            for (int off = 32; off > 0; off >>= 1) s += __shfl_xor(s, off, 64);
            alds[tid] = e / s;
        }
        __syncthreads();
        // ---- GEMM1: beta pre-activations
        f32x4 acc2[2][4];
        #pragma unroll
        for (int i = 0; i < 2; ++i)
            #pragma unroll
            for (int rt = 0; rt < 4; ++rt)
                #pragma unroll
                for (int j = 0; j < 4; ++j) acc2[i][rt][j] = bb2[i][j];
        #pragma unroll
        for (int kc = 0; kc < 8; ++kc) {
            half8 hb[4];
            #pragma unroll
            for (int rt = 0; rt < 4; ++rt)
                hb[rt] = *reinterpret_cast<const half8*>(&hs[(rt * 16 + lr) * 256 + ((kc * 32 + lg * 8) ^ ((lr & 7) << 3))]);
            #pragma unroll
            for (int i = 0; i < 2; ++i)
                #pragma unroll
                for (int rt = 0; rt < 4; ++rt)
                    acc2[i][rt] = __builtin_amdgcn_mfma_f32_16x16x32_f16(aw2[i][kc], hb[rt], acc2[i][rt], 0, 0, 0);
        }
        // ---- epilogue1: U (registers) + pred partial (ewh from LDS)
        float pv = 0.f;
        half4 ureg[2][4];
        #pragma unroll
        for (int i = 0; i < 2; ++i)
            #pragma unroll
            for (int rt = 0; rt < 4; ++rt) {
                int k = rt * 16 + lr;
                float al = alds[k];
                int d0 = (2 * w + i) * 16 + lg * 4;
                half4 ev4 = *reinterpret_cast<const half4*>(&es2[k * 256 + (d0 ^ ((lr & 7) << 3))]);
                #pragma unroll
                for (int j = 0; j < 4; ++j) {
                    float u = al * tanhfast_(acc2[i][rt][j]);
                    ureg[i][rt][j] = (_Float16)u;
                    pv += u * (float)ev4[j];
                }
            }
        __syncthreads();   // all hs reads done
        // ---- U -> hs (overwrite H), pred reduce
        #pragma unroll
        for (int i = 0; i < 2; ++i)
            #pragma unroll
            for (int rt = 0; rt < 4; ++rt) {
                int k = rt * 16 + lr;
                int d0 = (2 * w + i) * 16 + lg * 4;
                *reinterpret_cast<half4*>(&hs[k * 256 + (d0 ^ ((lr & 7) << 3))]) = ureg[i][rt];
            }
        #pragma unroll
        for (int off = 1; off < 64; off <<= 1) pv += __shfl_xor(pv, off, 64);
        if (l == 0) red2[w] = pv;
        __syncthreads();
        if (tid == 0) {
            float s = 0.f;
            #pragma unroll
            for (int q = 0; q < 8; ++q) s += red2[q];
            out[(size_t)b * P_ + p] = s + ob;
        }
        // ---- GEMM2: G = U @ M
        f32x4 a2[2][4];
        #pragma unroll
        for (int i = 0; i < 2; ++i)
            #pragma unroll
            for (int rt = 0; rt < 4; ++rt)
                #pragma unroll
                for (int j = 0; j < 4; ++j) a2[i][rt][j] = 0.f;
        #pragma unroll
        for (int kc = 0; kc < 8; ++kc) {
            half8 ub[4];
            #pragma unroll
            for (int rt = 0; rt < 4; ++rt)
                ub[rt] = *reinterpret_cast<const half8*>(&hs[(rt * 16 + lr) * 256 + ((kc * 32 + lg * 8) ^ ((lr & 7) << 3))]);
            #pragma unroll
            for (int i = 0; i < 2; ++i)
                #pragma unroll
                for (int rt = 0; rt < 4; ++rt)
                    a2[i][rt] = __builtin_amdgcn_mfma_f32_16x16x32_f16(am2[i][kc], ub[rt], a2[i][rt], 0, 0, 0);
        }
        // ---- epilogue2: weight = sum_k G*x /(p+1) (x from LDS)
        float r4[2][4];
        #pragma unroll
        for (int i = 0; i < 2; ++i)
            #pragma unroll
            for (int j = 0; j < 4; ++j) r4[i][j] = 0.f;
        #pragma unroll
        for (int i = 0; i < 2; ++i)
            #pragma unroll
            for (int rt = 0; rt < 4; ++rt) {
                int k = rt * 16 + lr;
                int i0 = (2 * w + i) * 16 + lg * 4;
                half4 xv4 = *reinterpret_cast<const half4*>(&xs2[k * 256 + (i0 ^ ((lr & 7) << 3))]);
                #pragma unroll
                for (int j = 0; j < 4; ++j) r4[i][j] += a2[i][rt][j] * (float)xv4[j];
            }
        #pragma unroll
        for (int off = 1; off < 16; off <<= 1)
            #pragma unroll
            for (int i = 0; i < 2; ++i)
                #pragma unroll
                for (int j = 0; j < 4; ++j) r4[i][j] += __shfl_xor(r4[i][j], off, 64);
        if (lr == 0) {
            float inv = 1.f / (float)(p + 1);
            #pragma unroll
            for (int i = 0; i < 2; ++i) {
                f32x4 v;
                #pragma unroll
                for (int j = 0; j < 4; ++j) v[j] = r4[i][j] * inv;
                *reinterpret_cast<f32x4*>(&out[2016 + ((size_t)b * P_ + p) * 256 + (2 * w + i) * 16 + lg * 4]) = v;
            }
        }
        __syncthreads();   // before next pair's staging
    }
}

// ---------------------------------------------------------------- host
extern "C" void kernel_launch(void* const* d_in, const int* in_sizes, int n_in,
                              void* d_out, int out_size, void* d_ws, size_t ws_size,
                              hipStream_t stream) {
    const float* x       = (const float*)d_in[0];
    const float* emb_w   = (const float*)d_in[1];
    const float* emb_b   = (const float*)d_in[2];
    const float* a_wih   = (const float*)d_in[3];
    const float* a_whh   = (const float*)d_in[4];
    const float* a_bih   = (const float*)d_in[5];
    const float* a_bhh   = (const float*)d_in[6];
    const float* b_wih   = (const float*)d_in[7];
    const float* b_whh   = (const float*)d_in[8];
    const float* b_bih   = (const float*)d_in[9];
    const float* b_bhh   = (const float*)d_in[10];
    const float* alpha_w = (const float*)d_in[11];
    const float* alpha_b = (const float*)d_in[12];
    const float* beta_w  = (const float*)d_in[13];
    const float* beta_b  = (const float*)d_in[14];
    const float* out_w   = (const float*)d_in[15];
    const float* out_b   = (const float*)d_in[16];
    float* out = (float*)d_out;

    float* ws = (float*)d_ws;
    _Float16* embh = (_Float16*)ws;                  // 262144 f
    _Float16* ewh  = embh + 524288;                  // 262144 f
    _Float16* xh   = ewh  + 524288;                  // 262144 f
    _Float16* gpa  = xh   + 524288;                  // 786432 f
    _Float16* gpb  = gpa  + 1572864;                 // 786432 f
    float* pre     = (float*)(gpb + 1572864);        // 129024 f
    _Float16* wfa  = (_Float16*)(pre + 129024);      // 98304 f
    _Float16* wfb  = wfa + 196608;                   // 98304 f
    _Float16* wifa = wfb + 196608;                   // 98304 f
    _Float16* wifb = wifa + 196608;                  // 98304 f
    _Float16* bwf  = wifb + 196608;                  // 32768 f
    _Float16* mf   = bwf + 65536;                    // 32768 f
    _Float16* hH   = mf  + 65536;                    // 8257536 f

    const int GRU_LDS = 98304 + 32768 + 2048;        // 133120 B
    (void)hipFuncSetAttribute((const void*)k_gru_f,
                              hipFuncAttributeMaxDynamicSharedMemorySize, GRU_LDS);
    const int ATT_LDS = 98304 + 256 + 32;            // 98592 B
    (void)hipFuncSetAttribute((const void*)k_att3,
                              hipFuncAttributeMaxDynamicSharedMemorySize, ATT_LDS);

    k_prep<<<1792, 64, 0, stream>>>(a_whh, b_whh, a_wih, b_wih, beta_w, emb_w, out_w,
                                    wfa, wfb, wifa, wifb, bwf, mf);
    k_emb<<<256, 256, 0, stream>>>(x, emb_w, emb_b, out_w, embh, ewh, xh);
    k_gates2<<<128, 512, 0, stream>>>(embh, wifa, wifb, a_bih, a_bhh, b_bih, b_bhh, gpa, gpb);
    k_gru_f<<<126, 512, GRU_LDS, stream>>>(gpa, gpb, wfa, wfb, a_bhh, b_bhh,
                                           alpha_w, alpha_b, pre, hH);
    k_att3<<<252, 512, ATT_LDS, stream>>>(hH, bwf, mf, beta_b, pre, ewh, xh, out_b, out);
}

// Round 18
// 286.798 us; speedup vs baseline: 2.0310x; 2.0310x over previous
//
#include <hip/hip_runtime.h>
#include <math.h>

// Problem constants: B=32, T=64, I=E=Ha=Hb=256, O=1, P=T-1=63
#define B_   32
#define T_   64
#define P_   63
#define E_   256

typedef _Float16 half8 __attribute__((ext_vector_type(8)));
typedef _Float16 half4 __attribute__((ext_vector_type(4)));
typedef float    f32x4 __attribute__((ext_vector_type(4)));

__device__ __forceinline__ float sigmoidf_(float x) { return 1.0f / (1.0f + __expf(-x)); }
__device__ __forceinline__ float tanhfast_(float x) { float e = __expf(2.0f*x); return 1.0f - 2.0f/(e + 1.0f); }

// Barrier WITHOUT vmcnt drain: only LDS ops must be visible across it.
__device__ __forceinline__ void barrier_lds_() {
    asm volatile("" ::: "memory");
    asm volatile("s_waitcnt lgkmcnt(0)" ::: "memory");
    __builtin_amdgcn_s_barrier();
    asm volatile("" ::: "memory");
}

// ---------------------------------------------------------------- K_prep: all weight->fp16 MFMA A-fragments, one launch.
__global__ __launch_bounds__(64) void k_prep(
    const float* __restrict__ awhh, const float* __restrict__ bwhh,
    const float* __restrict__ awih, const float* __restrict__ bwih,
    const float* __restrict__ beta_w, const float* __restrict__ emb_w, const float* __restrict__ out_w,
    _Float16* __restrict__ wfa, _Float16* __restrict__ wfb,
    _Float16* __restrict__ wifa, _Float16* __restrict__ wifb,
    _Float16* __restrict__ bwf, _Float16* __restrict__ mf)
{
    int bid = blockIdx.x, l = threadIdx.x;
    if (bid < 1664) {
        const float* W; _Float16* dst; float scale = 1.0f; int r;
        if (bid < 384)       { W = awhh;   dst = wfa;  r = bid; }
        else if (bid < 768)  { W = bwhh;   dst = wfb;  r = bid - 384; }
        else if (bid < 1152) { W = awih;   dst = wifa; r = bid - 768; }
        else if (bid < 1536) { W = bwih;   dst = wifb; r = bid - 1152; }
        else                 { W = beta_w; dst = bwf;  r = bid - 1536; scale = 0.5f; }
        int ot = r >> 3, kc = r & 7;
        int orow = ot * 16 + (l & 15);
        int c0   = kc * 32 + (l >> 4) * 8;
        half8 v;
        #pragma unroll
        for (int j = 0; j < 8; ++j) v[j] = (_Float16)(scale * W[(size_t)orow * 256 + c0 + j]);
        *reinterpret_cast<half8*>(&dst[((size_t)r * 64 + l) * 8]) = v;
    } else {
        int r = bid - 1664;     // M^T frags: A[row=i][k=e] = out_w[e]*emb_w[e][i]
        int ot = r >> 3, kc = r & 7;
        int i  = ot * 16 + (l & 15);
        int e0 = kc * 32 + (l >> 4) * 8;
        half8 v;
        #pragma unroll
        for (int j = 0; j < 8; ++j) v[j] = (_Float16)(out_w[e0 + j] * emb_w[(size_t)(e0 + j) * 256 + i]);
        *reinterpret_cast<half8*>(&mf[((size_t)r * 64 + l) * 8]) = v;
    }
}

// ---------------------------------------------------------------- K1: emb (8 rows/block) -> embh, ewh, xh (all fp16)
__global__ __launch_bounds__(256) void k_emb(const float* __restrict__ x,
                                             const float* __restrict__ emb_w,
                                             const float* __restrict__ emb_b,
                                             const float* __restrict__ out_w,
                                             _Float16* __restrict__ embh,
                                             _Float16* __restrict__ ewh,
                                             _Float16* __restrict__ xh) {
    int r0 = blockIdx.x * 8;       // row = t*32 + b
    int tid = threadIdx.x;
    __shared__ float xs[8][E_];
    for (int rr = 0; rr < 8; ++rr) {
        int row = r0 + rr, t = row >> 5, b = row & 31;
        float xv = x[((size_t)b * T_ + t) * E_ + tid];
        xs[rr][tid] = xv;
        xh[((size_t)b * T_ + t) * E_ + tid] = (_Float16)xv;
    }
    __syncthreads();
    float acc[8];
    #pragma unroll
    for (int rr = 0; rr < 8; ++rr) acc[rr] = 0.f;
    const float* wr = emb_w + (size_t)tid * E_;
    for (int c = 0; c < 256; c += 4) {
        float4 wv = *reinterpret_cast<const float4*>(wr + c);
        #pragma unroll
        for (int rr = 0; rr < 8; ++rr) {
            float4 ev = *reinterpret_cast<const float4*>(&xs[rr][c]);
            acc[rr] += wv.x * ev.x + wv.y * ev.y + wv.z * ev.z + wv.w * ev.w;
        }
    }
    float eb = emb_b[tid], ow = out_w[tid];
    #pragma unroll
    for (int rr = 0; rr < 8; ++rr) {
        float v = acc[rr] + eb;
        embh[(size_t)(r0 + rr) * E_ + tid] = (_Float16)v;
        ewh[(size_t)(r0 + rr) * E_ + tid]  = (_Float16)(v * ow);
    }
}

// ---------------------------------------------------------------- K2: gi = wih @ emb^T + bias via MFMA -> packed gp layout.
// gp[(((t*2+bh)*8+w)*3+g3)*512 + l*8 + e], e=i*4+j -> dim 32w+16i+lg*4+j, batch bh*16+lr.
__global__ __launch_bounds__(512, 2) void k_gates2(
    const _Float16* __restrict__ embh,
    const _Float16* __restrict__ wifa, const _Float16* __restrict__ wifb,
    const float* __restrict__ abih, const float* __restrict__ abhh,
    const float* __restrict__ bbih, const float* __restrict__ bbhh,
    _Float16* __restrict__ gpa, _Float16* __restrict__ gpb)
{
    __shared__ _Float16 esw[32 * E_];   // 16 KB swizzled emb rows (batch) for this t
    int bid = blockIdx.x;
    int g = bid >> 6, t = bid & 63;
    const _Float16* wif = g ? wifb : wifa;
    const float* bih = g ? bbih : abih;
    const float* bhh = g ? bbhh : abhh;
    _Float16* gp = g ? gpb : gpa;
    int tid = threadIdx.x, w = tid >> 6, l = tid & 63, lg = l >> 4, lr = l & 15;

    #pragma unroll
    for (int q = 0; q < 2; ++q) {
        int idx = q * 512 + tid;
        int b = idx >> 5, e0 = (idx & 31) * 8;
        half8 v = *reinterpret_cast<const half8*>(&embh[((size_t)t * 32 + b) * E_ + e0]);
        *reinterpret_cast<half8*>(&esw[b * E_ + (e0 ^ ((b & 7) << 3))]) = v;
    }
    half8 aw[3][2][8];
    #pragma unroll
    for (int g3 = 0; g3 < 3; ++g3)
        #pragma unroll
        for (int i = 0; i < 2; ++i)
            #pragma unroll
            for (int kc = 0; kc < 8; ++kc)
                aw[g3][i][kc] = *reinterpret_cast<const half8*>(
                    &wif[(((size_t)(g3 * 16 + 2 * w + i) * 8 + kc) * 64 + l) * 8]);
    f32x4 acc[3][2][2];
    #pragma unroll
    for (int g3 = 0; g3 < 3; ++g3)
        #pragma unroll
        for (int i = 0; i < 2; ++i)
            #pragma unroll
            for (int rt = 0; rt < 2; ++rt)
                #pragma unroll
                for (int j = 0; j < 4; ++j) {
                    int d = g3 * 256 + 32 * w + 16 * i + lg * 4 + j;
                    acc[g3][i][rt][j] = bih[d] + ((g3 < 2) ? bhh[d] : 0.f);
                }
    __syncthreads();
    #pragma unroll
    for (int kc = 0; kc < 8; ++kc) {
        half8 eb[2];
        #pragma unroll
        for (int rt = 0; rt < 2; ++rt)
            eb[rt] = *reinterpret_cast<const half8*>(
                &esw[(rt * 16 + lr) * E_ + ((kc * 32 + lg * 8) ^ ((lr & 7) << 3))]);
        #pragma unroll
        for (int g3 = 0; g3 < 3; ++g3)
            #pragma unroll
            for (int i = 0; i < 2; ++i)
                #pragma unroll
                for (int rt = 0; rt < 2; ++rt)
                    acc[g3][i][rt] = __builtin_amdgcn_mfma_f32_16x16x32_f16(
                        aw[g3][i][kc], eb[rt], acc[g3][i][rt], 0, 0, 0);
    }
    #pragma unroll
    for (int g3 = 0; g3 < 3; ++g3)
        #pragma unroll
        for (int rt = 0; rt < 2; ++rt) {
            half8 v;
            #pragma unroll
            for (int i = 0; i < 2; ++i)
                #pragma unroll
                for (int j = 0; j < 4; ++j) v[i * 4 + j] = (_Float16)acc[g3][i][rt][j];
            *reinterpret_cast<half8*>(
                &gp[((((size_t)t * 2 + rt) * 8 + w) * 3 + g3) * 512 + l * 8]) = v;
        }
}

// ---------------------------------------------------------------- K3: triangular GRU chains (R12-exact, best-known: 190 us).
__global__ __launch_bounds__(512, 2) void k_gru_f(
    const _Float16* __restrict__ gpa, const _Float16* __restrict__ gpb,
    const _Float16* __restrict__ wfa, const _Float16* __restrict__ wfb,
    const float* __restrict__ abhh, const float* __restrict__ bbhh,
    const float* __restrict__ alpha_w, const float* __restrict__ alpha_b,
    float* __restrict__ pre, _Float16* __restrict__ hstore)
{
    extern __shared__ char smem[];
    half8*    wlds = reinterpret_cast<half8*>(smem);              // 96 KB
    _Float16* hsp  = reinterpret_cast<_Float16*>(smem + 98304);   // 16 KB
    float*    red  = reinterpret_cast<float*>(smem + 98304 + 16384);  // [2][16][8]

    int bid = blockIdx.x;
    int p   = 62 - (bid >> 2);
    int g   = (bid >> 1) & 1;
    int bh  = bid & 1;
    int tid = threadIdx.x;
    int w = tid >> 6, l = tid & 63, lg = l >> 4, lr = l & 15;
    const _Float16* gp  = g ? gpb : gpa;
    const _Float16* wf  = g ? wfb : wfa;
    const float*    bhh = g ? bbhh : abhh;

    half8 wreg[3][2][6];
    #pragma unroll
    for (int g3 = 0; g3 < 3; ++g3)
        #pragma unroll
        for (int i = 0; i < 2; ++i) {
            int ot = g3 * 16 + 2 * w + i;
            #pragma unroll
            for (int kc = 0; kc < 6; ++kc)
                wreg[g3][i][kc] = *reinterpret_cast<const half8*>(&wf[((size_t)(ot * 8 + kc) * 64 + l) * 8]);
        }
    #pragma unroll
    for (int q = 0; q < 12; ++q) {
        int idx = q * 512 + tid;
        int ot = idx >> 7, kcs = (idx >> 6) & 1, l2 = idx & 63;
        wlds[idx] = *reinterpret_cast<const half8*>(&wf[((size_t)(ot * 8 + 6 + kcs) * 64 + l2) * 8]);
    }
    float bhn[2][4], awv[2][4];
    #pragma unroll
    for (int i = 0; i < 2; ++i)
        #pragma unroll
        for (int j = 0; j < 4; ++j) {
            int d = 32 * w + 16 * i + lg * 4 + j;
            bhn[i][j] = bhh[512 + d];
            awv[i][j] = alpha_w[d];
        }
    float ab = alpha_b[0];
    float hreg[2][4];
    #pragma unroll
    for (int i = 0; i < 2; ++i)
        #pragma unroll
        for (int j = 0; j < 4; ++j) hreg[i][j] = 0.f;
    __syncthreads();

    size_t tri = (size_t)p * (p + 1) / 2;

    for (int k = 0; k <= p; ++k) {
        int t_in = p - k;
        int wr = k & 1, rb = wr ^ 1;
        if (k > 0 && g == 0 && tid < 16) {
            float s = 0.f;
            #pragma unroll
            for (int q = 0; q < 8; ++q) s += red[(rb * 16 + tid) * 8 + q];
            pre[((size_t)p * T_ + (t_in + 1)) * B_ + bh * 16 + tid] = 0.5f * s + ab;
        }
        half8 gch[3];
        {
            const _Float16* gq = gp + (((size_t)(t_in * 2 + bh) * 8 + w) * 3) * 512 + l * 8;
            #pragma unroll
            for (int c = 0; c < 3; ++c)
                gch[c] = *reinterpret_cast<const half8*>(gq + (size_t)c * 512);
        }
        f32x4 acc[3][2];
        #pragma unroll
        for (int g3 = 0; g3 < 3; ++g3)
            #pragma unroll
            for (int i = 0; i < 2; ++i)
                #pragma unroll
                for (int j = 0; j < 4; ++j) acc[g3][i][j] = 0.f;
        if (k > 0) {
            half8 bhv[2];
            {
                int cb = (lg * 8) ^ ((lr & 7) << 3);
                bhv[0] = *reinterpret_cast<const half8*>(&hsp[(rb * 16 + lr) * 256 + cb]);
            }
            #pragma unroll
            for (int kc = 0; kc < 8; ++kc) {
                if (kc < 7) {
                    int cb = ((kc + 1) * 32 + lg * 8) ^ ((lr & 7) << 3);
                    bhv[(kc + 1) & 1] = *reinterpret_cast<const half8*>(&hsp[(rb * 16 + lr) * 256 + cb]);
                }
                if (kc < 6) {
                    #pragma unroll
                    for (int g3 = 0; g3 < 3; ++g3)
                        #pragma unroll
                        for (int i = 0; i < 2; ++i)
                            acc[g3][i] = __builtin_amdgcn_mfma_f32_16x16x32_f16(
                                wreg[g3][i][kc], bhv[kc & 1], acc[g3][i], 0, 0, 0);
                } else {
                    #pragma unroll
                    for (int g3 = 0; g3 < 3; ++g3)
                        #pragma unroll
                        for (int i = 0; i < 2; ++i) {
                            half8 wlv = wlds[((g3 * 16 + 2 * w + i) * 2 + (kc - 6)) * 64 + l];
                            acc[g3][i] = __builtin_amdgcn_mfma_f32_16x16x32_f16(
                                wlv, bhv[kc & 1], acc[g3][i], 0, 0, 0);
                        }
                }
            }
        }
        _Float16* hdst = hstore + ((tri + (size_t)k) * B_ + bh * 16 + lr) * (size_t)E_ + 32 * w + lg * 4;
        #pragma unroll
        for (int i = 0; i < 2; ++i) {
            half4 hh;
            #pragma unroll
            for (int j = 0; j < 4; ++j) {
                int e = i * 4 + j;
                float rg = sigmoidf_(acc[0][i][j] + (float)gch[0][e]);
                float zg = sigmoidf_(acc[1][i][j] + (float)gch[1][e]);
                float ng = tanhfast_((float)gch[2][e] + rg * (acc[2][i][j] + bhn[i][j]));
                float h  = (1.f - zg) * ng + zg * hreg[i][j];
                hreg[i][j] = h;
                hh[j] = (_Float16)h;
            }
            int ce = (32 * w + 16 * i + lg * 4) ^ ((lr & 7) << 3);
            *reinterpret_cast<half4*>(&hsp[(wr * 16 + lr) * 256 + ce]) = hh;
            if (g) *reinterpret_cast<half4*>(hdst + 16 * i) = hh;
        }
        if (!g) {
            float pa = 0.f;
            #pragma unroll
            for (int i = 0; i < 2; ++i)
                #pragma unroll
                for (int j = 0; j < 4; ++j) pa += hreg[i][j] * awv[i][j];
            pa += __shfl_xor(pa, 16, 64);
            pa += __shfl_xor(pa, 32, 64);
            if (l < 16) red[(wr * 16 + l) * 8 + w] = pa;
        }
        barrier_lds_();
    }
    if (g == 0 && tid < 16) {
        int wl = p & 1;
        float s = 0.f;
        #pragma unroll
        for (int q = 0; q < 8; ++q) s += red[(wl * 16 + tid) * 8 + q];
        pre[((size_t)p * T_ + 0) * B_ + bh * 16 + tid] = 0.5f * s + ab;
    }
}

// ---------------------------------------------------------------- K5: attention tail v3 (R12-exact known-good).
__global__ __launch_bounds__(512, 2) void k_att3(
    const _Float16* __restrict__ hH,
    const _Float16* __restrict__ bwf, const _Float16* __restrict__ mf,
    const float* __restrict__ beta_b,
    const float* __restrict__ pre,
    const _Float16* __restrict__ ewh, const _Float16* __restrict__ xh,
    const float* __restrict__ out_b,
    float* __restrict__ out)
{
    extern __shared__ char smem[];
    _Float16* hs   = reinterpret_cast<_Float16*>(smem);            // [64][256] swz: H then U
    _Float16* es2  = reinterpret_cast<_Float16*>(smem + 32768);    // [64][256] swz: ewh
    _Float16* xs2  = reinterpret_cast<_Float16*>(smem + 65536);    // [64][256] swz: x
    float*    alds = reinterpret_cast<float*>(smem + 98304);       // [64]
    float*    red2 = reinterpret_cast<float*>(smem + 98304 + 256); // [8]
    int tid = threadIdx.x, w = tid >> 6, l = tid & 63, lg = l >> 4, lr = l & 15;

    half8 aw2[2][8], am2[2][8];
    #pragma unroll
    for (int i = 0; i < 2; ++i)
        #pragma unroll
        for (int kc = 0; kc < 8; ++kc) {
            size_t fo = (((size_t)(2 * w + i) * 8 + kc) * 64 + l) * 8;
            aw2[i][kc] = *reinterpret_cast<const half8*>(&bwf[fo]);
            am2[i][kc] = *reinterpret_cast<const half8*>(&mf[fo]);
        }
    float bb2[2][4];
    #pragma unroll
    for (int i = 0; i < 2; ++i)
        #pragma unroll
        for (int j = 0; j < 4; ++j)
            bb2[i][j] = beta_b[(2 * w + i) * 16 + lg * 4 + j];
    float ob = out_b[0];

    for (int it = 0; it < 8; ++it) {
        int pair = blockIdx.x * 8 + it;
        int p = pair >> 5, b = pair & 31;
        size_t tri = (size_t)p * (p + 1) / 2;
        // ---- stage H (reversed), ewh, x (coalesced 16B, swizzled)
        #pragma unroll
        for (int q = 0; q < 4; ++q) {
            int idx = q * 512 + tid;
            int k = idx >> 5, e0 = (idx & 31) * 8;
            int sw = e0 ^ ((k & 7) << 3);
            half8 hv, ev;
            if (k <= p) {
                hv = *reinterpret_cast<const half8*>(&hH[((tri + (size_t)(p - k)) * B_ + b) * 256 + e0]);
                ev = *reinterpret_cast<const half8*>(&ewh[((size_t)k * B_ + b) * 256 + e0]);
            } else {
                #pragma unroll
                for (int j = 0; j < 8; ++j) { hv[j] = (_Float16)0.f; ev[j] = (_Float16)0.f; }
            }
            *reinterpret_cast<half8*>(&hs[k * 256 + sw])  = hv;
            *reinterpret_cast<half8*>(&es2[k * 256 + sw]) = ev;
            *reinterpret_cast<half8*>(&xs2[k * 256 + sw]) =
                *reinterpret_cast<const half8*>(&xh[((size_t)b * T_ + k) * 256 + e0]);
        }
        // ---- softmax on wave 0
        if (tid < 64) {
            float v = (tid <= p) ? pre[((size_t)p * T_ + tid) * B_ + b] : -3.4e38f;
            float m = v;
            #pragma unroll
            for (int off = 32; off > 0; off >>= 1) m = fmaxf(m, __shfl_xor(m, off, 64));
            float e = (tid <= p) ? __expf(v - m) : 0.f;
            float s = e;
            #pragma unroll
            for (int off = 32; off > 0; off >>= 1) s += __shfl_xor(s, off, 64);
            alds[tid] = e / s;
        }
        __syncthreads();
        // ---- GEMM1: beta pre-activations
        f32x4 acc2[2][4];
        #pragma unroll
        for (int i = 0; i < 2; ++i)
            #pragma unroll
            for (int rt = 0; rt < 4; ++rt)
                #pragma unroll
                for (int j = 0; j < 4; ++j) acc2[i][rt][j] = bb2[i][j];
        #pragma unroll
        for (int kc = 0; kc < 8; ++kc) {
            half8 hb[4];
            #pragma unroll
            for (int rt = 0; rt < 4; ++rt)
                hb[rt] = *reinterpret_cast<const half8*>(&hs[(rt * 16 + lr) * 256 + ((kc * 32 + lg * 8) ^ ((lr & 7) << 3))]);
            #pragma unroll
            for (int i = 0; i < 2; ++i)
                #pragma unroll
                for (int rt = 0; rt < 4; ++rt)
                    acc2[i][rt] = __builtin_amdgcn_mfma_f32_16x16x32_f16(aw2[i][kc], hb[rt], acc2[i][rt], 0, 0, 0);
        }
        // ---- epilogue1: U (registers) + pred partial (ewh from LDS)
        float pv = 0.f;
        half4 ureg[2][4];
        #pragma unroll
        for (int i = 0; i < 2; ++i)
            #pragma unroll
            for (int rt = 0; rt < 4; ++rt) {
                int k = rt * 16 + lr;
                float al = alds[k];
                int d0 = (2 * w + i) * 16 + lg * 4;
                half4 ev4 = *reinterpret_cast<const half4*>(&es2[k * 256 + (d0 ^ ((lr & 7) << 3))]);
                #pragma unroll
                for (int j = 0; j < 4; ++j) {
                    float u = al * tanhfast_(acc2[i][rt][j]);
                    ureg[i][rt][j] = (_Float16)u;
                    pv += u * (float)ev4[j];
                }
            }
        __syncthreads();   // all hs reads done
        // ---- U -> hs (overwrite H), pred reduce
        #pragma unroll
        for (int i = 0; i < 2; ++i)
            #pragma unroll
            for (int rt = 0; rt < 4; ++rt) {
                int k = rt * 16 + lr;
                int d0 = (2 * w + i) * 16 + lg * 4;
                *reinterpret_cast<half4*>(&hs[k * 256 + (d0 ^ ((lr & 7) << 3))]) = ureg[i][rt];
            }
        #pragma unroll
        for (int off = 1; off < 64; off <<= 1) pv += __shfl_xor(pv, off, 64);
        if (l == 0) red2[w] = pv;
        __syncthreads();
        if (tid == 0) {
            float s = 0.f;
            #pragma unroll
            for (int q = 0; q < 8; ++q) s += red2[q];
            out[(size_t)b * P_ + p] = s + ob;
        }
        // ---- GEMM2: G = U @ M
        f32x4 a2[2][4];
        #pragma unroll
        for (int i = 0; i < 2; ++i)
            #pragma unroll
            for (int rt = 0; rt < 4; ++rt)
                #pragma unroll
                for (int j = 0; j < 4; ++j) a2[i][rt][j] = 0.f;
        #pragma unroll
        for (int kc = 0; kc < 8; ++kc) {
            half8 ub[4];
            #pragma unroll
            for (int rt = 0; rt < 4; ++rt)
                ub[rt] = *reinterpret_cast<const half8*>(&hs[(rt * 16 + lr) * 256 + ((kc * 32 + lg * 8) ^ ((lr & 7) << 3))]);
            #pragma unroll
            for (int i = 0; i < 2; ++i)
                #pragma unroll
                for (int rt = 0; rt < 4; ++rt)
                    a2[i][rt] = __builtin_amdgcn_mfma_f32_16x16x32_f16(am2[i][kc], ub[rt], a2[i][rt], 0, 0, 0);
        }
        // ---- epilogue2: weight = sum_k G*x /(p+1) (x from LDS)
        float r4[2][4];
        #pragma unroll
        for (int i = 0; i < 2; ++i)
            #pragma unroll
            for (int j = 0; j < 4; ++j) r4[i][j] = 0.f;
        #pragma unroll
        for (int i = 0; i < 2; ++i)
            #pragma unroll
            for (int rt = 0; rt < 4; ++rt) {
                int k = rt * 16 + lr;
                int i0 = (2 * w + i) * 16 + lg * 4;
                half4 xv4 = *reinterpret_cast<const half4*>(&xs2[k * 256 + (i0 ^ ((lr & 7) << 3))]);
                #pragma unroll
                for (int j = 0; j < 4; ++j) r4[i][j] += a2[i][rt][j] * (float)xv4[j];
            }
        #pragma unroll
        for (int off = 1; off < 16; off <<= 1)
            #pragma unroll
            for (int i = 0; i < 2; ++i)
                #pragma unroll
                for (int j = 0; j < 4; ++j) r4[i][j] += __shfl_xor(r4[i][j], off, 64);
        if (lr == 0) {
            float inv = 1.f / (float)(p + 1);
            #pragma unroll
            for (int i = 0; i < 2; ++i) {
                f32x4 v;
                #pragma unroll
                for (int j = 0; j < 4; ++j) v[j] = r4[i][j] * inv;
                *reinterpret_cast<f32x4*>(&out[2016 + ((size_t)b * P_ + p) * 256 + (2 * w + i) * 16 + lg * 4]) = v;
            }
        }
        __syncthreads();   // before next pair's staging
    }
}

// ---------------------------------------------------------------- host
extern "C" void kernel_launch(void* const* d_in, const int* in_sizes, int n_in,
                              void* d_out, int out_size, void* d_ws, size_t ws_size,
                              hipStream_t stream) {
    const float* x       = (const float*)d_in[0];
    const float* emb_w   = (const float*)d_in[1];
    const float* emb_b   = (const float*)d_in[2];
    const float* a_wih   = (const float*)d_in[3];
    const float* a_whh   = (const float*)d_in[4];
    const float* a_bih   = (const float*)d_in[5];
    const float* a_bhh   = (const float*)d_in[6];
    const float* b_wih   = (const float*)d_in[7];
    const float* b_whh   = (const float*)d_in[8];
    const float* b_bih   = (const float*)d_in[9];
    const float* b_bhh   = (const float*)d_in[10];
    const float* alpha_w = (const float*)d_in[11];
    const float* alpha_b = (const float*)d_in[12];
    const float* beta_w  = (const float*)d_in[13];
    const float* beta_b  = (const float*)d_in[14];
    const float* out_w   = (const float*)d_in[15];
    const float* out_b   = (const float*)d_in[16];
    float* out = (float*)d_out;

    float* ws = (float*)d_ws;
    _Float16* embh = (_Float16*)ws;                  // 262144 f
    _Float16* ewh  = embh + 524288;                  // 262144 f
    _Float16* xh   = ewh  + 524288;                  // 262144 f
    _Float16* gpa  = xh   + 524288;                  // 786432 f
    _Float16* gpb  = gpa  + 1572864;                 // 786432 f
    float* pre     = (float*)(gpb + 1572864);        // 129024 f
    _Float16* wfa  = (_Float16*)(pre + 129024);      // 98304 f
    _Float16* wfb  = wfa + 196608;                   // 98304 f
    _Float16* wifa = wfb + 196608;                   // 98304 f
    _Float16* wifb = wifa + 196608;                  // 98304 f
    _Float16* bwf  = wifb + 196608;                  // 32768 f
    _Float16* mf   = bwf + 65536;                    // 32768 f
    _Float16* hH   = mf  + 65536;                    // 8257536 f

    const int GRU_LDS = 98304 + 16384 + 1024;        // 115712 B
    (void)hipFuncSetAttribute((const void*)k_gru_f,
                              hipFuncAttributeMaxDynamicSharedMemorySize, GRU_LDS);
    const int ATT_LDS = 98304 + 256 + 32;            // 98592 B
    (void)hipFuncSetAttribute((const void*)k_att3,
                              hipFuncAttributeMaxDynamicSharedMemorySize, ATT_LDS);

    k_prep<<<1792, 64, 0, stream>>>(a_whh, b_whh, a_wih, b_wih, beta_w, emb_w, out_w,
                                    wfa, wfb, wifa, wifb, bwf, mf);
    k_emb<<<256, 256, 0, stream>>>(x, emb_w, emb_b, out_w, embh, ewh, xh);
    k_gates2<<<128, 512, 0, stream>>>(embh, wifa, wifb, a_bih, a_bhh, b_bih, b_bhh, gpa, gpb);
    k_gru_f<<<252, 512, GRU_LDS, stream>>>(gpa, gpb, wfa, wfb, a_bhh, b_bhh,
                                           alpha_w, alpha_b, pre, hH);
    k_att3<<<252, 512, ATT_LDS, stream>>>(hH, bwf, mf, beta_b, pre, ewh, xh, out_b, out);
}